// Round 8
// baseline (126.228 us; speedup 1.0000x reference)
//
#include <hip/hip_runtime.h>
#include <hip/hip_bf16.h>
#include <math.h>

// Problem constants
#define NB    4096
#define DH    784
#define KX8   832            // fp8 row bytes: 784 padded to 13*64
#define NSR   5
#define NNEG  (NB*NSR)       // 20480
#define NTOT  (NB + NNEG)    // 24576

#define A_CONST 1.576943f
#define PEXP    1.7901216f   // 2*B_PARAM
#define EPS_C   1.0e-4f
#define ALPHA_C 0.9296875f   // BATCH_COUNT=500: beta=0.5*(1-500/800)^2=0.0703125
#define BETA_C  0.0703125f

#define NSLOT 64             // per row: 64 tile-contribs (row: slot=bj, col: slot=bi)
#define SLAB  (NB * NSLOT)   // elements per stat component = 262144
#define NBLK  2080           // upper-triangular 64x64 tile grid (8*260)

typedef __hip_bfloat16 bf16;
typedef short bf16x8 __attribute__((ext_vector_type(8)));
typedef float f32x4  __attribute__((ext_vector_type(4)));
typedef long long2v __attribute__((ext_vector_type(2)));

// Workspace layout (bytes)
#define WS_XF8    0                      // 4096*832   = 3407872
#define WS_EBF    3407872                // 4096*32*2  = 262144
#define WS_SQX    3670016                // 4096*4     = 16384
#define WS_SQE    3686400                // 4096*4     = 16384
#define WS_STATSP 3702784                // 5*262144*4 = 5242880
#define WS_UPART  8945664                // 96*4       = 384
#define WS_CPART  8946048                // 64*4       = 256
#define WS_CNT    8946304                // 4

// ---- fused prep: blocks 0..1023 -> X cast to fp8-e4m3, column-permuted layout
// (64B chunk c: dest dword p=4q+2h+w sources src dword c*16+h*8+q*2+w, so a
// lane's 16B at quad*16 = [K-half0 cols 8q..8q+7 | K-half1 cols 32+8q..+7]).
// COALESCED reads (lane walks src), permuted writes (stores don't stall).
// blocks 1024..1119 -> UMAP CE partials + e_to bf16 prep.
__global__ void prep_fused(const float* __restrict__ X, const float* __restrict__ emb,
                           const int* __restrict__ perm, unsigned char* __restrict__ Xf8,
                           float* __restrict__ sqx, bf16* __restrict__ Ebf,
                           float* __restrict__ sqe, float* __restrict__ upart,
                           unsigned* __restrict__ cnt) {
    if (blockIdx.x == 0 && threadIdx.x == 0) *cnt = 0u;   // for finish1 last-block
    if (blockIdx.x < 1024) {
        const int wave = threadIdx.x >> 6, lane = threadIdx.x & 63;
        const int row = blockIdx.x * 4 + wave;
        const float4* xr = (const float4*)(X + (size_t)row * DH);
        int* xb = (int*)(Xf8 + (size_t)row * KX8);
        float s = 0.f;
        #pragma unroll
        for (int it = 0; it < 4; ++it) {
            const int src = lane + it * 64;     // src float4 index 0..255
            if (src < 208) {
                int pk = 0;
                if (src < 196) {
                    float4 v = xr[src];
                    s += v.x * v.x + v.y * v.y + v.z * v.z + v.w * v.w;
                    int lo = __builtin_amdgcn_cvt_pk_fp8_f32(v.x, v.y, 0, false);
                    pk = __builtin_amdgcn_cvt_pk_fp8_f32(v.z, v.w, lo, true);
                }
                const int c = src >> 4, sc = src & 15;
                const int h = sc >> 3, q = (sc >> 1) & 3, w = sc & 1;
                xb[c * 16 + q * 4 + h * 2 + w] = pk;
            }
        }
        #pragma unroll
        for (int off = 32; off; off >>= 1) s += __shfl_down(s, off, 64);
        if (lane == 0) sqx[row] = s;
        return;
    }
    // UMAP CE + e_to bf16 prep
    const int ub = blockIdx.x - 1024;
    const int t = ub * 256 + threadIdx.x;
    float val = 0.f;
    if (t < NB) {
        const float4* av = (const float4*)(emb + (size_t)t * 32);
        float4 t0 = av[0], t1 = av[1], t2 = av[2], t3 = av[3];   // e_to
        float4 f0 = av[4], f1 = av[5], f2 = av[6], f3 = av[7];   // e_from
        bf16* eb = Ebf + (size_t)t * 32;
        union { bf16 h[4]; ushort4 u; } cv;
        #define ST4(dst, q) cv.h[0]=__float2bfloat16(q.x); cv.h[1]=__float2bfloat16(q.y); \
                            cv.h[2]=__float2bfloat16(q.z); cv.h[3]=__float2bfloat16(q.w); \
                            *(ushort4*)(dst) = cv.u;
        ST4(eb,      t0) ST4(eb + 4,  t1) ST4(eb + 8,  t2) ST4(eb + 12, t3)
        #undef ST4
        ushort4 z = {0, 0, 0, 0};
        *(ushort4*)(eb + 16) = z; *(ushort4*)(eb + 20) = z;
        *(ushort4*)(eb + 24) = z; *(ushort4*)(eb + 28) = z;
        sqe[t] = t0.x*t0.x + t0.y*t0.y + t0.z*t0.z + t0.w*t0.w
               + t1.x*t1.x + t1.y*t1.y + t1.z*t1.z + t1.w*t1.w
               + t2.x*t2.x + t2.y*t2.y + t2.z*t2.z + t2.w*t2.w
               + t3.x*t3.x + t3.y*t3.y + t3.z*t3.z + t3.w*t3.w;
        float d2 = 0.f;
        #define D2(a, b) { float4 df = {a.x-b.x, a.y-b.y, a.z-b.z, a.w-b.w}; \
                           d2 += df.x*df.x + df.y*df.y + df.z*df.z + df.w*df.w; }
        D2(t0, f0) D2(t1, f1) D2(t2, f2) D2(t3, f3)
        #undef D2
        float d = sqrtf(d2);
        float p = 1.f / (1.f + A_CONST * powf(d, PEXP));
        val = -logf(fminf(fmaxf(p, EPS_C), 1.f));
    } else if (t < NTOT) {
        const int k = t - NB;
        const int ti = k / 5;
        const int fi = perm[k] / 5;
        const float4* at = (const float4*)(emb + (size_t)ti * 32);
        const float4* bt = (const float4*)(emb + (size_t)fi * 32 + 16);
        float d2 = 0.f;
        #pragma unroll
        for (int q = 0; q < 4; ++q) {
            float4 a = at[q], b = bt[q];
            float4 df = {a.x-b.x, a.y-b.y, a.z-b.z, a.w-b.w};
            d2 += df.x*df.x + df.y*df.y + df.z*df.z + df.w*df.w;
        }
        float d = sqrtf(d2);
        float p = 1.f / (1.f + A_CONST * powf(d, PEXP));
        val = -logf(fminf(fmaxf(1.f - p, EPS_C), 1.f));
    }
    #pragma unroll
    for (int off = 32; off; off >>= 1) val += __shfl_down(val, off, 64);
    __shared__ float ps[4];
    if ((threadIdx.x & 63) == 0) ps[threadIdx.x >> 6] = val;
    __syncthreads();
    if (threadIdx.x == 0) upart[ub] = ps[0] + ps[1] + ps[2] + ps[3];
}

// ---- main: upper-triangular 64x64 fp8 X-gram per 64-thread (1-wave) block.
// REGISTER staging (global_load_dwordx4 per fragment): NO LDS, NO barriers —
// compiler pipelines loads with fine-grained vmcnt, waves fully self-paced.
// Double-buffered fragment registers, bf16 E-gram + stats epilogue.
__global__ __launch_bounds__(64, 2) void gram_kernel(
    const unsigned char* __restrict__ Xf8, const bf16* __restrict__ Ebf,
    const float* __restrict__ sqx, const float* __restrict__ sqe,
    float* __restrict__ statsp) {
    // XCD swizzle: 2080 = 8*260; XCD k gets 260 consecutive triangle entries.
    int n = (blockIdx.x & 7) * 260 + (blockIdx.x >> 3);
    int bi = 0;
    while (n >= 64 - bi) { n -= 64 - bi; ++bi; }
    const int bj = bi + n;
    const int i0 = bi * 64, j0 = bj * 64;

    const int lane = threadIdx.x;
    const int quad = lane >> 4, l15 = lane & 15;

    f32x4 acc[4][4];
    #pragma unroll
    for (int a = 0; a < 4; ++a)
        #pragma unroll
        for (int b = 0; b < 4; ++b)
            acc[a][b] = (f32x4){0.f, 0.f, 0.f, 0.f};

    // per-mi fragment base pointers (stage offset fits the 13-bit imm)
    const unsigned char* pam[4];
    const unsigned char* pbm[4];
    #pragma unroll
    for (int mi = 0; mi < 4; ++mi) {
        pam[mi] = Xf8 + (size_t)(i0 + mi * 16 + l15) * KX8 + quad * 16;
        pbm[mi] = Xf8 + (size_t)(j0 + mi * 16 + l15) * KX8 + quad * 16;
    }

    long2v a0[4], b0[4], a1[4], b1[4];
    #pragma unroll
    for (int mi = 0; mi < 4; ++mi) {
        a0[mi] = *(const long2v*)(pam[mi]);
        b0[mi] = *(const long2v*)(pbm[mi]);
    }
    #define MFMA_SET(af, bf) \
        _Pragma("unroll") \
        for (int mi = 0; mi < 4; ++mi) \
            _Pragma("unroll") \
            for (int ni = 0; ni < 4; ++ni) { \
                acc[mi][ni] = __builtin_amdgcn_mfma_f32_16x16x32_fp8_fp8( \
                    af[mi][0], bf[ni][0], acc[mi][ni], 0, 0, 0); \
                acc[mi][ni] = __builtin_amdgcn_mfma_f32_16x16x32_fp8_fp8( \
                    af[mi][1], bf[ni][1], acc[mi][ni], 0, 0, 0); \
            }
    #pragma unroll
    for (int p = 0; p < 6; ++p) {
        const int s1 = (2 * p + 1) * 64, s2 = (2 * p + 2) * 64;
        #pragma unroll
        for (int mi = 0; mi < 4; ++mi) {
            a1[mi] = *(const long2v*)(pam[mi] + s1);
            b1[mi] = *(const long2v*)(pbm[mi] + s1);
        }
        MFMA_SET(a0, b0)
        #pragma unroll
        for (int mi = 0; mi < 4; ++mi) {
            a0[mi] = *(const long2v*)(pam[mi] + s2);
            b0[mi] = *(const long2v*)(pbm[mi] + s2);
        }
        MFMA_SET(a1, b1)
    }

    // issue E-fragment + sq-norm loads before the last MFMA set (overlap)
    const unsigned char* pea = (const unsigned char*)Ebf + (size_t)(i0 + l15) * 64 + quad * 16;
    const unsigned char* peb = (const unsigned char*)Ebf + (size_t)(j0 + l15) * 64 + quad * 16;
    bf16x8 afE[4], bfE[4];
    #pragma unroll
    for (int mi = 0; mi < 4; ++mi) {
        afE[mi] = *(const bf16x8*)(pea + mi * 1024);
        bfE[mi] = *(const bf16x8*)(peb + mi * 1024);
    }
    float sqxi[16], sqei[16];   // [mi*4+r] for i = i0 + mi*16 + quad*4 + r
    #pragma unroll
    for (int mi = 0; mi < 4; ++mi)
        #pragma unroll
        for (int r = 0; r < 4; ++r) {
            sqxi[mi * 4 + r] = sqx[i0 + mi * 16 + quad * 4 + r];
            sqei[mi * 4 + r] = sqe[i0 + mi * 16 + quad * 4 + r];
        }
    float sqxj[4], sqej[4];     // for j = j0 + ni*16 + l15
    #pragma unroll
    for (int ni = 0; ni < 4; ++ni) {
        sqxj[ni] = sqx[j0 + ni * 16 + l15];
        sqej[ni] = sqe[j0 + ni * 16 + l15];
    }

    MFMA_SET(a0, b0)            // stage 12
    #undef MFMA_SET

    // Epilogue. C/D layout: col = lane&15, row = quad*4 + reg  [m89/m91]
    // Row-stats (sum over j): slot bj. Col-stats (bi<bj): slot bi.
    // Per strip s, slots {bj>=s} u {bi<s} = 0..63 exactly once.
    float cH[4] = {0,0,0,0}, cH2[4] = {0,0,0,0}, cL[4] = {0,0,0,0},
          cL2[4] = {0,0,0,0}, cHL[4] = {0,0,0,0};
    #pragma unroll
    for (int mi = 0; mi < 4; ++mi) {
        f32x4 aE[4];
        #pragma unroll
        for (int ni = 0; ni < 4; ++ni) {
            f32x4 z = (f32x4){0.f, 0.f, 0.f, 0.f};
            aE[ni] = __builtin_amdgcn_mfma_f32_16x16x32_bf16(afE[mi], bfE[ni], z, 0, 0, 0);
        }
        const int ilocb = mi * 16 + quad * 4;
        float sH[4] = {0,0,0,0}, sH2[4] = {0,0,0,0}, sL[4] = {0,0,0,0},
              sL2[4] = {0,0,0,0}, sHL[4] = {0,0,0,0};
        #pragma unroll
        for (int ni = 0; ni < 4; ++ni) {
            const int j = j0 + ni * 16 + l15;
            #pragma unroll
            for (int r = 0; r < 4; ++r) {
                const int i = i0 + ilocb + r;
                float H, L;
                if (i == j) { H = 0.f; L = 0.f; }
                else {
                    float d2  = sqxi[mi * 4 + r] + sqxj[ni] - 2.0f * acc[mi][ni][r];
                    H = sqrtf(fmaxf(d2, 0.f));
                    float d2e = sqei[mi * 4 + r] + sqej[ni] - 2.0f * aE[ni][r];
                    L = sqrtf(fmaxf(d2e, 0.f));
                }
                sH[r] += H; sH2[r] += H * H; sL[r] += L; sL2[r] += L * L; sHL[r] += H * L;
                cH[ni] += H; cH2[ni] += H * H; cL[ni] += L; cL2[ni] += L * L; cHL[ni] += H * L;
            }
        }
        #pragma unroll
        for (int r = 0; r < 4; ++r) {
            float v0 = sH[r], v1 = sH2[r], v2 = sL[r], v3 = sL2[r], v4 = sHL[r];
            #pragma unroll
            for (int off2 = 1; off2 < 16; off2 <<= 1) {   // reduce over l15
                v0 += __shfl_xor(v0, off2, 64);
                v1 += __shfl_xor(v1, off2, 64);
                v2 += __shfl_xor(v2, off2, 64);
                v3 += __shfl_xor(v3, off2, 64);
                v4 += __shfl_xor(v4, off2, 64);
            }
            if (l15 == 0) {
                const int i = i0 + ilocb + r;
                float* base = statsp + (size_t)bj * NB + i;   // [c][slot][i]
                base[0 * SLAB] = v0;
                base[1 * SLAB] = v1;
                base[2 * SLAB] = v2;
                base[3 * SLAB] = v3;
                base[4 * SLAB] = v4;
            }
        }
    }
    if (bi != bj) {
        #pragma unroll
        for (int ni = 0; ni < 4; ++ni) {
            float v0 = cH[ni], v1 = cH2[ni], v2 = cL[ni], v3 = cL2[ni], v4 = cHL[ni];
            #pragma unroll
            for (int off2 = 16; off2 < 64; off2 <<= 1) {   // reduce over quad
                v0 += __shfl_xor(v0, off2, 64);
                v1 += __shfl_xor(v1, off2, 64);
                v2 += __shfl_xor(v2, off2, 64);
                v3 += __shfl_xor(v3, off2, 64);
                v4 += __shfl_xor(v4, off2, 64);
            }
            if (quad == 0) {
                const int j = j0 + ni * 16 + l15;
                float* base = statsp + (size_t)bi * NB + j;
                base[0 * SLAB] = v0;
                base[1 * SLAB] = v1;
                base[2 * SLAB] = v2;
                base[3 * SLAB] = v3;
                base[4 * SLAB] = v4;
            }
        }
    }
}

// ---- finish1: reduce 64 slots per row, per-row corr; last block folds partials -> out
__global__ void finish1_kernel(const float* __restrict__ statsp, const float* __restrict__ upart,
                               float* __restrict__ cpart, unsigned* __restrict__ cnt,
                               float* __restrict__ out) {
    __shared__ float ps2[4][64][5];
    const int t = threadIdx.x;
    const int rloc = t & 63;
    const int sg = t >> 6;
    const int r = blockIdx.x * 64 + rloc;
    float sh = 0.f, sh2 = 0.f, sl = 0.f, sl2 = 0.f, shl = 0.f;
    for (int s = sg * 16; s < sg * 16 + 16; ++s) {
        const float* base = statsp + (size_t)s * NB + r;
        sh  += base[0 * SLAB];
        sh2 += base[1 * SLAB];
        sl  += base[2 * SLAB];
        sl2 += base[3 * SLAB];
        shl += base[4 * SLAB];
    }
    ps2[sg][rloc][0] = sh; ps2[sg][rloc][1] = sh2; ps2[sg][rloc][2] = sl;
    ps2[sg][rloc][3] = sl2; ps2[sg][rloc][4] = shl;
    __syncthreads();
    if (t < 64) {
        float a = 0.f, b = 0.f, c = 0.f, d = 0.f, e = 0.f;
        #pragma unroll
        for (int g = 0; g < 4; ++g) {
            a += ps2[g][t][0]; b += ps2[g][t][1]; c += ps2[g][t][2];
            d += ps2[g][t][3]; e += ps2[g][t][4];
        }
        const float invN = 1.0f / (float)NB;
        float num = e - a * c * invN;
        float vh  = fmaxf(b - a * a * invN, 0.f);
        float vl  = fmaxf(d - c * c * invN, 0.f);
        float local = num / (sqrtf(vh) * sqrtf(vl));
        #pragma unroll
        for (int off = 32; off; off >>= 1) local += __shfl_down(local, off, 64);
        if (t == 0) cpart[blockIdx.x] = local;
    }
    // last block folds 64 corr partials + 96 umap partials into the loss
    __shared__ int lastFlag;
    if (t == 0) {
        __threadfence();                       // cpart store visible device-wide
        unsigned prev = atomicAdd(cnt, 1u);
        lastFlag = (prev == 63u);
    }
    __syncthreads();
    if (lastFlag) {
        __threadfence();                       // acquire other blocks' cpart
        float v = 0.f;
        if (t < 64) v += cpart[t] * (-BETA_C / (float)NB);
        if (t < 96) v += upart[t] * (ALPHA_C / (float)NTOT);
        #pragma unroll
        for (int off = 32; off; off >>= 1) v += __shfl_down(v, off, 64);
        __shared__ float fin[4];
        if ((t & 63) == 0) fin[t >> 6] = v;
        __syncthreads();
        if (t == 0) out[0] = fin[0] + fin[1] + fin[2] + fin[3];
    }
}

extern "C" void kernel_launch(void* const* d_in, const int* in_sizes, int n_in,
                              void* d_out, int out_size, void* d_ws, size_t ws_size,
                              hipStream_t stream) {
    const float* emb  = (const float*)d_in[0];   // (4096, 32) f32
    const float* ph   = (const float*)d_in[1];   // (4096, 784) f32
    const int*   perm = (const int*)d_in[2];     // (20480,) i32
    float* out = (float*)d_out;

    char* ws = (char*)d_ws;
    unsigned char* Xf8 = (unsigned char*)(ws + WS_XF8);
    bf16*  Ebf    = (bf16*) (ws + WS_EBF);
    float* sqx    = (float*)(ws + WS_SQX);
    float* sqe    = (float*)(ws + WS_SQE);
    float* statsp = (float*)(ws + WS_STATSP);
    float* upart  = (float*)(ws + WS_UPART);
    float* cpart  = (float*)(ws + WS_CPART);
    unsigned* cnt = (unsigned*)(ws + WS_CNT);

    prep_fused<<<1120, 256, 0, stream>>>(ph, emb, perm, Xf8, sqx, Ebf, sqe, upart, cnt);
    gram_kernel<<<NBLK, 64, 0, stream>>>(Xf8, Ebf, sqx, sqe, statsp);
    finish1_kernel<<<64, 256, 0, stream>>>(statsp, upart, cpart, cnt, out);
}